// Round 19
// baseline (24.516 us; speedup 1.0000x reference)
//
#include <hip/hip_runtime.h>

#define TWO_PI 6.2831853071795864769f

// ONE dispatch, NO cross-block sync, NO ws. Grid = 96 blocks, blk = h*8+b
// (XCD swizzle); b>=6 exit. One block per (h,b) chain, 1024 threads.
//
// r19 change vs r11 (single variable): m-fill via global_load_lds DMA
// double-buffer pipeline instead of plain vector loads. Evidence: plain
// loads pin at ~10 B/cyc/CU regardless of order/source/nt (r11/r13/r17/r18);
// m97's GEMM sustains ~22 B/cyc/CU through global_load_lds. Pipeline:
// 16 chunks x (16 rows x 1KB x {P1,P3}), 2 LDS bufs, counted vmcnt(2) +
// raw s_barrier (never drain-0 in loop), 2 barriers/chunk for buffer reuse.
// Each wave issues 2 DMAs/chunk and consumes row dg via ds_read_b128 into
// m4[16] (m4[j] = row j*16+dg). Hash/init moved AFTER the fill (vmcnt
// accounting must stay clean during the pipeline).
__global__ __launch_bounds__(1024, 4) void fused_chain(
    const float* __restrict__ P1, const float* __restrict__ P2,
    const float* __restrict__ P3, const float* __restrict__ T4,
    const int* __restrict__ p5, const int* __restrict__ p6,
    const int* __restrict__ p7, const int* __restrict__ p8,
    const float* __restrict__ f1, const float* __restrict__ ph1,
    const float* __restrict__ T11, const float* __restrict__ f2,
    const float* __restrict__ ph2, const float* __restrict__ T14,
    const float* __restrict__ f3, const float* __restrict__ ph3,
    float* __restrict__ out, int K)
{
    const int blk = (int)blockIdx.x;
    const int b = blk & 7;               // = blk % 8 = XCD id
    if (b >= 6) return;
    const int h = blk >> 3;              // 0..11

    __shared__ float sP1[2][4096];         // 32 KB staging (16 rows x 1KB)
    __shared__ float sP3[2][4096];         // 32 KB staging
    __shared__ float v[256];
    __shared__ unsigned hmap_pv[4096];     // 16 KB: hash (fill) / pv (stages)
    __shared__ float modl[3][256];
    __shared__ unsigned short wde[2048];   // winner (d<<8)|e
    __shared__ float wv0[2048], wv1[2048], wv2[2048];
    __shared__ int nw;

    const int tid = (int)threadIdx.x;
    const int dg = tid >> 6;               // wave id 0..15
    const int eg = tid & 63;               // lane
    const int lane4 = eg << 2;             // float offset of this lane

    // ---- phase 1: DMA pipeline, m4[j] = M[row j*16+dg][eg*4..+3] ----
    float4 m4[16];
    // per-wave DMA issue: chunk c -> rows (b,c*16+dg); wave dg stages row dg
    // of the chunk for both arrays. LDS dest wave-uniform, global src per-lane.
    #define ISSUE_CHUNK(c, buf)                                               \
        do {                                                                  \
            const float* g1 = P1 + ((((b << 8) + ((c) << 4) + dg)) << 8) + lane4; \
            const float* g3 = P3 + ((((b << 8) + ((c) << 4) + dg)) << 8) + lane4; \
            __builtin_amdgcn_global_load_lds(                                 \
                (const __attribute__((address_space(1))) void*)g1,            \
                (__attribute__((address_space(3))) void*)&sP1[buf][dg << 8],  \
                16, 0, 0);                                                    \
            __builtin_amdgcn_global_load_lds(                                 \
                (const __attribute__((address_space(1))) void*)g3,            \
                (__attribute__((address_space(3))) void*)&sP3[buf][dg << 8],  \
                16, 0, 0);                                                    \
        } while (0)

    ISSUE_CHUNK(0, 0);
    ISSUE_CHUNK(1, 1);
    #pragma unroll
    for (int c = 0; c < 16; ++c) {
        // wait own DMAs for chunk c (2 instrs/chunk; allow 2 newer chunks)
        if (c == 15) asm volatile("s_waitcnt vmcnt(0)" ::: "memory");
        else         asm volatile("s_waitcnt vmcnt(4)" ::: "memory");
        __builtin_amdgcn_sched_barrier(0);
        __builtin_amdgcn_s_barrier();      // chunk c resident for all waves
        float4 a = *(const float4*)&sP1[c & 1][(dg << 8) + lane4];
        float4 p = *(const float4*)&sP3[c & 1][(dg << 8) + lane4];
        m4[c].x = fmaf(p.x, 0.975f, a.x);
        m4[c].y = fmaf(p.y, 0.975f, a.y);
        m4[c].z = fmaf(p.z, 0.975f, a.z);
        m4[c].w = fmaf(p.w, 0.975f, a.w);
        asm volatile("s_waitcnt lgkmcnt(0)" ::: "memory");
        __builtin_amdgcn_sched_barrier(0);
        __builtin_amdgcn_s_barrier();      // all waves consumed buf[c&1]
        if (c + 2 < 16) ISSUE_CHUNK(c + 2, c & 1);
    }
    #undef ISSUE_CHUNK

    // ---- phase 2: init + hash (post-fill; ~1.5us, vmcnt now unconstrained) ----
    if (tid < 256) v[tid] = P2[(h * 6 + b) * 256 + tid];
    if (tid < 768) {
        int s = tid >> 8, ee = tid & 255;
        float fr = (s == 0) ? f1[0]  : (s == 1) ? f2[0]  : f3[0];
        float ph = (s == 0) ? ph1[0] : (s == 1) ? ph2[0] : ph3[0];
        float sn = __sinf((float)ee * TWO_PI * fr + ph);
        float mm = sn * sn * 0.1f + 0.95f;
        modl[s][ee] = (s == 1) ? mm : 1.0f / mm;   // s0: /m, s1: *m, s2: /m
    }
    for (int i = tid; i < 4096; i += 1024) hmap_pv[i] = 0xFFFFFFFFu;
    if (tid == 0) nw = 0;
    __syncthreads();

    for (int k = tid; k < K; k += 1024) {
        if (p5[k] != b) continue;
        unsigned key = ((unsigned)p7[k] << 8) | (unsigned)p8[k];
        unsigned mine = (key << 12) | (unsigned)k;       // k < 4096
        unsigned hh = (key * 2654435761u) >> 20;         // [0,4096)
        for (;;) {
            unsigned prev = atomicCAS(&hmap_pv[hh], 0xFFFFFFFFu, mine);
            if (prev == 0xFFFFFFFFu) break;
            if ((prev >> 12) == key) { atomicMax(&hmap_pv[hh], mine); break; }
            hh = (hh + 1) & 4095u;
        }
    }
    __syncthreads();

    for (int k = tid; k < K; k += 1024) {
        if (p5[k] != b) continue;
        unsigned key = ((unsigned)p7[k] << 8) | (unsigned)p8[k];
        unsigned hh = (key * 2654435761u) >> 20;
        unsigned cur;
        for (;;) {
            cur = hmap_pv[hh];
            if ((cur >> 12) == key) break;
            hh = (hh + 1) & 4095u;
        }
        if ((cur & 0xFFFu) == (unsigned)k) {             // last write wins
            int c = p6[k];
            float p1v = P1[(b << 16) | key];
            int w = atomicAdd(&nw, 1);
            wde[w] = (unsigned short)key;
            wv0[w] = T4 [b * 256 + c] - p1v;
            wv1[w] = T11[b * 256 + c] - p1v;
            wv2[w] = T14[b * 256 + c] - p1v;
        }
    }
    __syncthreads();
    const int nwl = nw;

    // ---- phase 3: three chained stages (pv aliases hmap space) ----
    float (*pv)[256] = (float(*)[256])hmap_pv;
    const int e256 = tid & 255;
    for (int s = 0; s < 3; ++s) {
        float4 acc = make_float4(0.f, 0.f, 0.f, 0.f);
        #pragma unroll
        for (int j = 0; j < 16; ++j) {
            float vv = v[(j << 4) + dg];   // wave-uniform LDS broadcast
            acc.x = fmaf(vv, m4[j].x, acc.x);
            acc.y = fmaf(vv, m4[j].y, acc.y);
            acc.z = fmaf(vv, m4[j].z, acc.z);
            acc.w = fmaf(vv, m4[j].w, acc.w);
        }
        *(float4*)&pv[dg][lane4] = acc;
        __syncthreads();
        {   // reduce 16 -> 4 rows
            int r = tid >> 8;                       // 0..3
            float x = pv[r][e256] + pv[r + 4][e256] +
                      pv[r + 8][e256] + pv[r + 12][e256];
            __syncthreads();
            pv[r][e256] = x;
        }
        __syncthreads();
        if (tid < 256)                              // reduce 4 -> 1
            pv[0][tid] = (pv[0][tid] + pv[1][tid]) + (pv[2][tid] + pv[3][tid]);
        __syncthreads();
        const float* wvs = (s == 0) ? wv0 : (s == 1) ? wv1 : wv2;
        for (int i = tid; i < nwl; i += 1024) {
            unsigned de = wde[i];
            atomicAdd(&pv[0][de & 255u], v[de >> 8] * wvs[i]);
        }
        __syncthreads();
        if (tid < 256)
            v[tid] = pv[0][tid] * modl[s][tid];
        __syncthreads();
    }
    if (tid < 256) out[(h * 6 + b) * 256 + tid] = v[tid];
}

extern "C" void kernel_launch(void* const* d_in, const int* in_sizes, int n_in,
                              void* d_out, int out_size, void* d_ws, size_t ws_size,
                              hipStream_t stream)
{
    (void)n_in; (void)out_size; (void)d_ws; (void)ws_size;
    const float* P1  = (const float*)d_in[0];
    const float* P2  = (const float*)d_in[1];
    const float* P3  = (const float*)d_in[2];
    const float* T4  = (const float*)d_in[3];
    const int*   p5  = (const int*)d_in[4];
    const int*   p6  = (const int*)d_in[5];
    const int*   p7  = (const int*)d_in[6];
    const int*   p8  = (const int*)d_in[7];
    const float* f1  = (const float*)d_in[8];
    const float* ph1 = (const float*)d_in[9];
    const float* T11 = (const float*)d_in[10];
    const float* f2  = (const float*)d_in[11];
    const float* ph2 = (const float*)d_in[12];
    const float* T14 = (const float*)d_in[13];
    const float* f3  = (const float*)d_in[14];
    const float* ph3 = (const float*)d_in[15];
    float* out = (float*)d_out;
    int K = in_sizes[4];

    hipLaunchKernelGGL(fused_chain, dim3(96), dim3(1024), 0, stream,
                       P1, P2, P3, T4, p5, p6, p7, p8,
                       f1, ph1, T11, f2, ph2, T14, f3, ph3, out, K);
}